// Round 17
// baseline (1561.296 us; speedup 1.0000x reference)
//
#include <hip/hip_runtime.h>
#include <cstdint>
#include <cstddef>

// ---------------------------------------------------------------------------
// TLSTM: B=64, S=512, I=256, H=256
// R17 = R16 with the compile fix: global_load imm offset is 13-bit SIGNED
// (max 4095), so the 8-slice register gather uses two base pointers with
// offsets 0..3072 each. Design unchanged:
// 8 shards x 8 groups (grid 64), all exchange sc0+sc1 device-scope (IC),
// register-gather pipeline, 2 barriers/step, wave-4 wide publish + tag,
// 64-lane broadcast tag poll. Messages few+wide, polls few+tiny.
// ---------------------------------------------------------------------------

#define B_   64
#define S_   512
#define H_   256
#define BSH_ ((size_t)B_ * S_ * H_)  // 8388608

typedef _Float16 f16;
typedef _Float16 f16x8 __attribute__((ext_vector_type(8)));
typedef short    s16x8 __attribute__((ext_vector_type(8)));
typedef float    f32x4 __attribute__((ext_vector_type(4)));
typedef unsigned int u32x4 __attribute__((ext_vector_type(4)));

static __device__ __forceinline__ unsigned short f32_to_bf16(float f) {
    union { float f; uint32_t u; } v; v.f = f;
    uint32_t u = v.u;
    u += 0x7fffu + ((u >> 16) & 1u);   // RTNE
    return (unsigned short)(u >> 16);
}

static __device__ __forceinline__ float sigm(float z) {
    return 1.0f / (1.0f + __expf(-z));
}
static __device__ __forceinline__ float tanh_fast(float z) {
    float e = __expf(-2.0f * fabsf(z));
    float t = (1.0f - e) / (1.0f + e);
    return z >= 0.0f ? t : -t;
}

// ---------------------------------------------------------------------------
// prep: W4 (bf16, [1024][256]) + fused bias4 (Wg_b + b_g + Ug_b)
// ---------------------------------------------------------------------------
__global__ void prep_w4(const float* __restrict__ Wi, const float* __restrict__ Wf,
                        const float* __restrict__ Wo, const float* __restrict__ Wc,
                        const float* __restrict__ Wib, const float* __restrict__ Wfb,
                        const float* __restrict__ Wob, const float* __restrict__ Wcb,
                        const float* __restrict__ Uib, const float* __restrict__ Ufb,
                        const float* __restrict__ Uob, const float* __restrict__ Ucb,
                        const float* __restrict__ bi,  const float* __restrict__ bf_,
                        const float* __restrict__ bo,  const float* __restrict__ bc,
                        unsigned short* __restrict__ W4, float* __restrict__ bias4) {
    const int n = blockIdx.x;        // 0..1023
    const int k = threadIdx.x;       // 0..255
    const int g = n >> 8, o = n & 255;
    const float* W = (g == 0) ? Wi : (g == 1) ? Wf : (g == 2) ? Wo : Wc;
    W4[n * 256 + k] = f32_to_bf16(W[o * 256 + k]);
    if (k == 0) {
        const float* wb = (g == 0) ? Wib : (g == 1) ? Wfb : (g == 2) ? Wob : Wcb;
        const float* ub = (g == 0) ? Uib : (g == 1) ? Ufb : (g == 2) ? Uob : Ucb;
        const float* sb = (g == 0) ? bi  : (g == 1) ? bf_ : (g == 2) ? bo  : bc;
        bias4[n] = wb[o] + ub[o] + sb[o];
    }
}

// ---------------------------------------------------------------------------
// prep: weight B-fragments, 8-shard layout, fragment-linear:
// wfg[ q*5120 + ((g*2+t)*8+ks)*64 + l ] = f16x8 of
//   U_g[ 32q + t*16 + (l&15) ][ 32ks + (l>>4)*8 .. +8 ]
// ---------------------------------------------------------------------------
__global__ void prep_wfrag(const float* __restrict__ Ui, const float* __restrict__ Uf,
                           const float* __restrict__ Uo, const float* __restrict__ Uc,
                           const float* __restrict__ Wd, uint4* __restrict__ wfg) {
    const int id = blockIdx.x * 256 + threadIdx.x;   // 0..40959
    const int l  = id & 63;
    const int ks = (id >> 6) & 7;
    const int t  = (id >> 9) & 1;
    const int qg = id >> 10;         // q*5+g, 0..39
    const int q  = qg / 5;
    const int g  = qg - q * 5;
    const float* U = (g == 0) ? Ui : (g == 1) ? Uf : (g == 2) ? Uo : (g == 3) ? Uc : Wd;
    const int row = 32 * q + t * 16 + (l & 15);
    const int k0  = 32 * ks + (l >> 4) * 8;
    const float* src = U + (size_t)row * 256 + k0;
    union { f16 h[8]; uint4 v; } pk;
    #pragma unroll
    for (int i = 0; i < 8; ++i) pk.h[i] = (f16)src[i];
    wfg[id] = pk.v;
}

// prep: Tm1[m] = 1/log(ts+2.7183) - 1
__global__ void prep_T(const float* __restrict__ tsp, float* __restrict__ Tm1) {
    const int i = blockIdx.x * 256 + threadIdx.x;   // 0..32767
    Tm1[i] = 1.0f / logf(tsp[i] + 2.7183f) - 1.0f;
}

// zero n dwords at p (runs every launch; graph replays it)
__global__ void prep_zero(unsigned int* __restrict__ p, int n) {
    const int i = blockIdx.x * 256 + threadIdx.x;
    if (i < n) p[i] = 0u;
}

// ---------------------------------------------------------------------------
// Projection GEMM: Xbuf[m][j][g] f16 (gate-interleaved; recur reads uint2).
// ---------------------------------------------------------------------------
__global__ __launch_bounds__(256) void proj_gemm(const float* __restrict__ X,
        const unsigned short* __restrict__ W4, const float* __restrict__ bias4,
        f16* __restrict__ Xbuf) {
    __shared__ __align__(16) unsigned short a_s[64 * 40];
    __shared__ __align__(16) unsigned short b_s[64 * 40];
    const int bid = blockIdx.x;
    const int m0 = (bid >> 4) * 64;
    const int n0 = (bid & 15) * 64;
    const int tid  = threadIdx.x;
    const int lane = tid & 63;
    const int w    = tid >> 6;
    const int srow = tid >> 2;
    const int scol = (tid & 3) * 8;
    const int r  = lane & 15;
    const int kg = lane >> 4;

    f32x4 acc[4] = {{0,0,0,0},{0,0,0,0},{0,0,0,0},{0,0,0,0}};

    for (int kt = 0; kt < 8; ++kt) {
        const int k0 = kt * 32;
        float4 av0 = *reinterpret_cast<const float4*>(X + (size_t)(m0 + srow) * 256 + k0 + scol);
        float4 av1 = *reinterpret_cast<const float4*>(X + (size_t)(m0 + srow) * 256 + k0 + scol + 4);
        union { unsigned short us[8]; uint4 v; } pk;
        pk.us[0] = f32_to_bf16(av0.x); pk.us[1] = f32_to_bf16(av0.y);
        pk.us[2] = f32_to_bf16(av0.z); pk.us[3] = f32_to_bf16(av0.w);
        pk.us[4] = f32_to_bf16(av1.x); pk.us[5] = f32_to_bf16(av1.y);
        pk.us[6] = f32_to_bf16(av1.z); pk.us[7] = f32_to_bf16(av1.w);
        *reinterpret_cast<uint4*>(a_s + srow * 40 + scol) = pk.v;
        uint4 bv = *reinterpret_cast<const uint4*>(W4 + (size_t)(n0 + srow) * 256 + k0 + scol);
        *reinterpret_cast<uint4*>(b_s + srow * 40 + scol) = bv;
        __syncthreads();

        s16x8 af = *reinterpret_cast<const s16x8*>(a_s + (w * 16 + r) * 40 + kg * 8);
        #pragma unroll
        for (int nt = 0; nt < 4; ++nt) {
            s16x8 bfr = *reinterpret_cast<const s16x8*>(b_s + (nt * 16 + r) * 40 + kg * 8);
            acc[nt] = __builtin_amdgcn_mfma_f32_16x16x32_bf16(af, bfr, acc[nt], 0, 0, 0);
        }
        __syncthreads();
    }
    #pragma unroll
    for (int nt = 0; nt < 4; ++nt) {
        const int n = n0 + nt * 16 + r;
        const int gidx = n >> 8, jj = n & 255;
        const float bn = bias4[n];
        #pragma unroll
        for (int reg = 0; reg < 4; ++reg) {
            const int m = m0 + w * 16 + kg * 4 + reg;
            Xbuf[((size_t)m * 256 + jj) * 4 + gidx] = (f16)(acc[nt][reg] + bn);
        }
    }
}

// ---------------------------------------------------------------------------
// Recurrence. Grid 64: G = bid&7 (group), q = bid>>3 (shard, rows [32q,32q+32)
// of all five matrices, 80KB LDS). Group = 8 blocks serving batches 8G..8G+7.
// ---------------------------------------------------------------------------
__global__ __launch_bounds__(320) void recur(
        const uint4* __restrict__ wfg, const f16* __restrict__ Xbuf,
        const float* __restrict__ Wdb, const float* __restrict__ bdv,
        const float* __restrict__ Tm1,
        uint4* __restrict__ hxf, uint4* __restrict__ cxf,
        unsigned int* __restrict__ tags, float* __restrict__ out) {
    extern __shared__ __align__(16) char smemraw[];
    uint4* wfr  = (uint4*)smemraw;            // 5120 units (80KB)
    float* pre  = (float*)(wfr + 5120);       // [16][164] f32 (10496B)
    f16*   stgh = (f16*)(pre + 16 * 164);     // 256 f16 (512B)
    f16*   stgc = stgh + 256;                 // 256 f16
    float* obh  = (float*)(stgc + 256);       // [8][256] f32 (8KB)
    float* obc  = obh + 2048;                 // [8][256] f32

    const int tid = threadIdx.x;
    const int bid = blockIdx.x;
    const int G = bid & 7;           // batch group
    const int q = bid >> 3;          // row shard 0..7
    const int g = tid >> 6;          // wave = matrix 0..4
    const int l = tid & 63;

    // ---- stage weight frags ----
    {
        const uint4* src = wfg + (size_t)q * 5120;
        #pragma unroll
        for (int i = 0; i < 16; ++i) wfr[tid + i * 320] = src[tid + i * 320];
    }
    const int gb = tid >> 5;         // batch-lane 0..7 (tid<256)
    const int jl = tid & 31;         // local j 0..31
    const int j  = 32 * q + jl;      // hidden index
    float cj = 0.0f, bD = 0.0f;
    if (tid < 256) bD = Wdb[j] + bdv[j];
    __syncthreads();

    uint4* hxb = hxf + (size_t)G * 1024;       // [par][512]
    uint4* cxb = cxf + (size_t)G * 1024;
    unsigned int* tg = tags + (size_t)G * 256; // [par][8 slots x 16dw]

    // loop-carried A-slices (h for waves 0-3, c for wave 4); start = state 0
    f16x8 A[8];
    #pragma unroll
    for (int p = 0; p < 8; ++p) A[p] = (f16x8)(f16)0;

    for (int s = 0; s < 512; ++s) {
        const int par = s & 1;

        // prefetch gate inputs (consumed after B1)
        uint2 xv = {0, 0};
        float tm1 = 0.f;
        if (tid < 256) {
            const size_t m = (size_t)(8 * G + gb) * 512 + s;
            xv  = *reinterpret_cast<const uint2*>(Xbuf + (m * 256 + j) * 4);
            tm1 = Tm1[m];
        }

        // ---- MFMA matvec from register A-slices: 2 N-tiles x 8 K-steps ----
        f32x4 acc0 = {0.f, 0.f, 0.f, 0.f};
        f32x4 acc1 = {0.f, 0.f, 0.f, 0.f};
        #pragma unroll
        for (int p = 0; p < 8; ++p) {
            f16x8 b0 = __builtin_bit_cast(f16x8, wfr[((g * 2 + 0) * 8 + p) * 64 + l]);
            f16x8 b1 = __builtin_bit_cast(f16x8, wfr[((g * 2 + 1) * 8 + p) * 64 + l]);
            acc0 = __builtin_amdgcn_mfma_f32_16x16x32_f16(A[p], b0, acc0, 0, 0, 0);
            acc1 = __builtin_amdgcn_mfma_f32_16x16x32_f16(A[p], b1, acc1, 0, 0, 0);
        }
        {
            const int mb = (l >> 4) * 4;          // batch base (D rows)
            const int c0 = g * 32 + (l & 15);     // tile0 col
            #pragma unroll
            for (int reg = 0; reg < 4; ++reg) {
                pre[(mb + reg) * 164 + c0]      = acc0[reg];
                pre[(mb + reg) * 164 + c0 + 16] = acc1[reg];
            }
        }
        __syncthreads();                          // B1: preacts ready

        // ---- gates (threads 0..255: one (batch,j) pair) ----
        if (tid < 256) {
            const float* pb = pre + gb * 164;
            const f16* xp = reinterpret_cast<const f16*>(&xv);
            float CST  = tanh_fast(pb[128 + jl] + bD);
            float cdec = cj + tm1 * CST;
            float ig = sigm((float)xp[0] + pb[jl]);
            float fg = sigm((float)xp[1] + pb[32 + jl]);
            float og = sigm((float)xp[2] + pb[64 + jl]);
            float Cn = tanh_fast((float)xp[3] + pb[96 + jl]);
            cj = fg * cdec + ig * Cn;
            float hn = og * tanh_fast(cj);
            obh[(s & 7) * 256 + tid] = hn;
            obc[(s & 7) * 256 + tid] = cj;
            stgh[tid] = (f16)hn;                  // [gb*32 + jl]
            stgc[tid] = (f16)cj;
        }
        __syncthreads();                          // B2: staging ready

        if (s != 511) {
            // ---- wave 4: wide publish (64 x 16B) + vmcnt + tag ----
            if (g == 4) {
                const int lm = l & 31;
                const int kg = lm >> 3, b = lm & 7;
                const bool isC = l >= 32;
                u32x4 v = __builtin_bit_cast(u32x4, *reinterpret_cast<const uint4*>(
                    (isC ? stgc : stgh) + b * 32 + kg * 8));
                uint4* pp = (isC ? cxb : hxb) + par * 512 + q * 64 + kg * 16 + b;
                asm volatile("global_store_dwordx4 %0, %1, off sc0 sc1"
                             :: "v"(pp), "v"(v) : "memory");
                asm volatile("s_waitcnt vmcnt(0)" ::: "memory");
                if (l == 0) {
                    unsigned int* tp = tg + par * 128 + q * 16;
                    unsigned tv = (unsigned)(s + 1);
                    asm volatile("global_store_dword %0, %1, off sc0 sc1"
                                 :: "v"(tp), "v"(tv) : "memory");
                }
            }
        }
        // ---- output flush every 8 steps (overlaps publish/poll) ----
        if ((s & 7) == 7 && tid < 256) {
            #pragma unroll
            for (int sf = 0; sf < 8; ++sf) {
                const size_t mm = (size_t)(8 * G + gb) * 512 + (s - 7 + sf);
                const size_t oi = mm * 256 + j;
                float hv = obh[sf * 256 + tid];
                float cv = obc[sf * 256 + tid];
                out[oi] = hv; out[BSH_ + oi] = hv; out[2 * BSH_ + oi] = cv;
            }
        }
        if (s != 511) {
            // ---- all waves: poll 8 tags (4B broadcast loads, __all) ----
            {
                const unsigned tgt = (unsigned)(s + 1);
                const unsigned int* tp = tg + par * 128 + (l & 7) * 16;
                unsigned v; int spins = 0;
                for (;;) {
                    asm volatile("global_load_dword %0, %1, off sc0 sc1\n\t"
                                 "s_waitcnt vmcnt(0)"
                                 : "=v"(v) : "v"(tp) : "memory");
                    if (__all((int)(v >= tgt))) break;
                    if (++spins > (1 << 18)) break;   // fail-fast insurance
                    __builtin_amdgcn_s_sleep(1);
                }
            }
            // ---- register gather: 8 slices x 16B per lane, 2 bases x 4 ----
            {
                const uint4* base0 = ((g == 4) ? cxb : hxb) + par * 512 + l;
                const uint4* base1 = base0 + 256;   // +4096 B
                u32x4 r0, r1, r2, r3, r4, r5, r6, r7;
                asm volatile(
                    "global_load_dwordx4 %0, %8, off sc0 sc1\n\t"
                    "global_load_dwordx4 %1, %8, off offset:1024 sc0 sc1\n\t"
                    "global_load_dwordx4 %2, %8, off offset:2048 sc0 sc1\n\t"
                    "global_load_dwordx4 %3, %8, off offset:3072 sc0 sc1\n\t"
                    "global_load_dwordx4 %4, %9, off sc0 sc1\n\t"
                    "global_load_dwordx4 %5, %9, off offset:1024 sc0 sc1\n\t"
                    "global_load_dwordx4 %6, %9, off offset:2048 sc0 sc1\n\t"
                    "global_load_dwordx4 %7, %9, off offset:3072 sc0 sc1\n\t"
                    "s_waitcnt vmcnt(0)"
                    : "=&v"(r0), "=&v"(r1), "=&v"(r2), "=&v"(r3),
                      "=&v"(r4), "=&v"(r5), "=&v"(r6), "=&v"(r7)
                    : "v"(base0), "v"(base1)
                    : "memory");
                A[0] = __builtin_bit_cast(f16x8, r0);
                A[1] = __builtin_bit_cast(f16x8, r1);
                A[2] = __builtin_bit_cast(f16x8, r2);
                A[3] = __builtin_bit_cast(f16x8, r3);
                A[4] = __builtin_bit_cast(f16x8, r4);
                A[5] = __builtin_bit_cast(f16x8, r5);
                A[6] = __builtin_bit_cast(f16x8, r6);
                A[7] = __builtin_bit_cast(f16x8, r7);
            }
        }
        // no trailing barrier: B1/B2 of the next iteration provide ordering
    }
}

// ---------------------------------------------------------------------------
extern "C" void kernel_launch(void* const* d_in, const int* in_sizes, int n_in,
                              void* d_out, int out_size, void* d_ws, size_t ws_size,
                              hipStream_t stream) {
    const float* inputs = (const float*)d_in[0];
    const float* tsp    = (const float*)d_in[1];
    const float* Wi_w = (const float*)d_in[2],  * Wi_b = (const float*)d_in[3];
    const float* Ui_w = (const float*)d_in[4],  * Ui_b = (const float*)d_in[5];
    const float* Wf_w = (const float*)d_in[6],  * Wf_b = (const float*)d_in[7];
    const float* Uf_w = (const float*)d_in[8],  * Uf_b = (const float*)d_in[9];
    const float* Wo_w = (const float*)d_in[10], * Wo_b = (const float*)d_in[11];
    const float* Uo_w = (const float*)d_in[12], * Uo_b = (const float*)d_in[13];
    const float* Wc_w = (const float*)d_in[14], * Wc_b = (const float*)d_in[15];
    const float* Uc_w = (const float*)d_in[16], * Uc_b = (const float*)d_in[17];
    const float* Wd_w = (const float*)d_in[18], * Wd_b = (const float*)d_in[19];
    const float* bi = (const float*)d_in[20], * bf_ = (const float*)d_in[21];
    const float* bo = (const float*)d_in[22], * bc  = (const float*)d_in[23];
    const float* bd = (const float*)d_in[24];

    // workspace layout (16B-aligned):
    //   Xbuf  f16   [32768][256][4]  67,108,864 B @ 0
    //   W4    bf16  [1024][256]         524,288 B @ 67,108,864
    //   bias4 f32   [1024]                4,096 B @ 67,633,152
    //   wfg   uint4 [40960]             655,360 B @ 67,637,248
    //   hxf   uint4 [8][2][512]         131,072 B @ 68,292,608   <- zeroed
    //   cxf   uint4 [8][2][512]         131,072 B @ 68,423,680   <- zeroed
    //   tags  u32   [8][2][8][16]         8,192 B @ 68,554,752   <- zeroed
    //   Tm1   f32   [32768]             131,072 B @ 68,562,944
    char* ws = (char*)d_ws;
    f16*            Xbuf  = (f16*)ws;
    unsigned short* W4    = (unsigned short*)(ws + 67108864);
    float*          bias4 = (float*)(ws + 67633152);
    uint4*          wfg   = (uint4*)(ws + 67637248);
    uint4*          hxf   = (uint4*)(ws + 68292608);
    uint4*          cxf   = (uint4*)(ws + 68423680);
    unsigned int*   tags  = (unsigned int*)(ws + 68554752);
    float*          Tm1   = (float*)(ws + 68562944);

    prep_w4<<<1024, 256, 0, stream>>>(Wi_w, Wf_w, Wo_w, Wc_w,
                                      Wi_b, Wf_b, Wo_b, Wc_b,
                                      Ui_b, Uf_b, Uo_b, Uc_b,
                                      bi, bf_, bo, bc, W4, bias4);
    prep_wfrag<<<160, 256, 0, stream>>>(Ui_w, Uf_w, Uo_w, Uc_w, Wd_w, wfg);
    prep_T<<<128, 256, 0, stream>>>(tsp, Tm1);
    // zero hxf+cxf+tags (contiguous, 270,336 B = 67,584 dwords)
    prep_zero<<<264, 256, 0, stream>>>((unsigned int*)hxf, 67584);
    proj_gemm<<<8192, 256, 0, stream>>>(inputs, W4, bias4, Xbuf);

    const size_t lds_bytes = 5120 * 16 + 16 * 164 * 4
                           + 2 * 256 * 2 + 2 * 2048 * 4;   // 109,824 B
    recur<<<64, 320, lds_bytes, stream>>>(wfg, Xbuf, Wd_b, bd, Tm1,
                                          hxf, cxf, tags, (float*)d_out);
}